// Round 8
// baseline (603.848 us; speedup 1.0000x reference)
//
#include <hip/hip_runtime.h>

#define N_NODES 100000
#define N_EDGES 1600000
#define DIM 128
#define NGRAPH 64
#define M_PAD 100096   // 782 * 128 = 1564 * 64
#define NBUCKET 782    // ceil(100000 / 128)
#define BCAP 4096      // staging capacity per bucket (mean 2046, sigma ~45)
#define CHUNK 8192     // edges per scatter block
#define XBLOCKS 12500  // N_NODES*DIM/4/256 — x2bf conversion blocks

typedef __attribute__((ext_vector_type(8))) short bf16x8;
typedef __attribute__((ext_vector_type(4))) float floatx4;

static __device__ __forceinline__ unsigned int f2bf(float f) {
    unsigned int u = __builtin_bit_cast(unsigned int, f);
    return (u + 0x7FFFu + ((u >> 16) & 1u)) >> 16;
}
static __device__ __forceinline__ float bf2f(unsigned short b) {
    unsigned int u = ((unsigned int)b) << 16;
    return __builtin_bit_cast(float, u);
}

// ---------------- fused conversions: x -> bf16, 3x W -> transposed bf16 ----------------

__global__ void k_convert(const float* __restrict__ x, unsigned short* __restrict__ xb,
                          const float* __restrict__ Wl1, const float* __restrict__ Wr1,
                          unsigned short* __restrict__ Wt1,
                          const float* __restrict__ Wl2, const float* __restrict__ Wr2,
                          unsigned short* __restrict__ Wt2,
                          const float* __restrict__ Wl3, const float* __restrict__ Wr3,
                          unsigned short* __restrict__ Wt3) {
    int b = blockIdx.x;
    if (b < XBLOCKS) {
        size_t i = (size_t)(b * 256 + threadIdx.x) * 4;
        float4 v = *(const float4*)(x + i);
        uint2 o;
        o.x = f2bf(v.x) | (f2bf(v.y) << 16);
        o.y = f2bf(v.z) | (f2bf(v.w) << 16);
        *(uint2*)(xb + i) = o;
    } else {
        int layer = (b - XBLOCKS) >> 7;
        const float* Wl = layer == 0 ? Wl1 : (layer == 1 ? Wl2 : Wl3);
        const float* Wr = layer == 0 ? Wr1 : (layer == 1 ? Wr2 : Wr3);
        unsigned short* Wt = layer == 0 ? Wt1 : (layer == 1 ? Wt2 : Wt3);
        int id = ((b - XBLOCKS) & 127) * 256 + threadIdx.x;  // 0..32767
        int n = id >> 8, k = id & 255;
        float v = (k < 128) ? Wl[k * 128 + n] : Wr[(k - 128) * 128 + n];
        Wt[n * 256 + k] = (unsigned short)f2bf(v);
    }
}

// ---------------- bucketed CSR build (unchanged from round 7) ----------------

__global__ __launch_bounds__(1024) void k_scatter2(const int* __restrict__ src,
                                                   const int* __restrict__ dst,
                                                   int* __restrict__ bcur,
                                                   unsigned int* __restrict__ staging) {
    __shared__ int cnt[NBUCKET];
    __shared__ int gbase[NBUCKET];
    __shared__ int pos[NBUCKET];
    int tid = threadIdx.x;
    int e0 = blockIdx.x * CHUNK;
    for (int i = tid; i < NBUCKET; i += 1024) {
        cnt[i] = 0;
        pos[i] = 0;
    }
    __syncthreads();
    int s[8], d[8];
#pragma unroll
    for (int j = 0; j < 8; j++) {
        int e = e0 + j * 1024 + tid;
        if (e < N_EDGES) {
            s[j] = src[e];
            d[j] = dst[e];
            atomicAdd(&cnt[d[j] >> 7], 1);
        } else {
            d[j] = -1;
        }
    }
    __syncthreads();
    for (int i = tid; i < NBUCKET; i += 1024) {
        int c = cnt[i];
        if (c > 0) gbase[i] = atomicAdd(&bcur[i], c);
    }
    __syncthreads();
#pragma unroll
    for (int j = 0; j < 8; j++) {
        if (d[j] >= 0) {
            int b = d[j] >> 7;
            int gp = gbase[b] + atomicAdd(&pos[b], 1);
            if (gp < BCAP)
                staging[(size_t)b * BCAP + gp] =
                    (unsigned int)s[j] | ((unsigned int)(d[j] & 127) << 25);
        }
    }
}

__global__ void k_bscan(const int* __restrict__ bcnt, int* __restrict__ bbase) {
    __shared__ int s[256];
    int tid = threadIdx.x;
    int v[4];
    int sum = 0;
#pragma unroll
    for (int j = 0; j < 4; j++) {
        int idx = tid * 4 + j;
        v[j] = (idx < NBUCKET) ? bcnt[idx] : 0;
        sum += v[j];
    }
    s[tid] = sum;
    __syncthreads();
    for (int off = 1; off < 256; off <<= 1) {
        int t = (tid >= off) ? s[tid - off] : 0;
        __syncthreads();
        s[tid] += t;
        __syncthreads();
    }
    int run = s[tid] - sum;
#pragma unroll
    for (int j = 0; j < 4; j++) {
        int idx = tid * 4 + j;
        if (idx <= NBUCKET) bbase[idx] = run;
        run += v[j];
    }
}

__global__ __launch_bounds__(256) void k_bsort(const unsigned int* __restrict__ staging,
                                               const int* __restrict__ bbase,
                                               int* __restrict__ rowptr,
                                               int* __restrict__ col) {
    __shared__ unsigned int lpk[BCAP];
    __shared__ int lcol[BCAP];
    __shared__ int loff[129];
    __shared__ int lcur[128];
    int b = blockIdx.x, tid = threadIdx.x;
    int gbase = bbase[b];
    int nE = bbase[b + 1] - gbase;
    if (nE > BCAP) nE = BCAP;
    if (tid < 128) {
        loff[tid] = 0;
        lcur[tid] = 0;
    }
    __syncthreads();
    const unsigned int* sb = staging + (size_t)b * BCAP;
    for (int i = tid; i < nE; i += 256) {
        unsigned int p = sb[i];
        lpk[i] = p;
        atomicAdd(&loff[p >> 25], 1);
    }
    __syncthreads();
    if (tid < 64) {
        int c0 = loff[2 * tid], c1 = loff[2 * tid + 1];
        int ps = c0 + c1;
        for (int off = 1; off < 64; off <<= 1) {
            int t = __shfl_up(ps, off);
            if (tid >= off) ps += t;
        }
        int excl = ps - (c0 + c1);
        loff[2 * tid] = excl;
        loff[2 * tid + 1] = excl + c0;
        if (tid == 63) loff[128] = ps;
    }
    __syncthreads();
    if (tid < 128) {
        int idx = b * 128 + tid;
        if (idx < N_NODES) rowptr[idx] = gbase + loff[tid];
    }
    if (tid == 0 && b == NBUCKET - 1) rowptr[N_NODES] = N_EDGES;
    for (int i = tid; i < nE; i += 256) {
        unsigned int p = lpk[i];
        int d = p >> 25;
        int pos = loff[d] + atomicAdd(&lcur[d], 1);
        lcol[pos] = (int)(p & 0x1FFFFFFu);
    }
    __syncthreads();
    for (int i = tid; i < nE; i += 256) col[gbase + i] = lcol[i];
}

// ---------------- fused SAGE layer: gather -> LDS (frag-swizzled) -> MFMA ----------------
// Block = 256 thr = 4 waves = 64 nodes. Phase A: wave w gathers nodes
// i0+w*16..+15 (r5-proven 2-deep quarter loop), packs bf16 rows into A_sw in
// MFMA A-fragment order: element (row r, k) at ((rt*4+ks)*4+q)*256 + t*16
// bytes, rt=r>>4, t=r&15, ks=k>>5, q=(k>>3)&3. Writer lane t (holding k in
// [8t,8t+8)) maps exactly: 32*(t>>2)+8*(t&3)+j == 8t+j.
// Phase C: K-blocks 0..3 read A-frags from LDS (lane-contiguous b128, zero
// conflicts); K-blocks 4..7 read h-frags from global (L2-hot). Cols split
// 32/wave; bias+ReLU epilogue; bf16 store.

template <bool RELU>
__global__ __launch_bounds__(256) void k_layer(
    const unsigned short* __restrict__ hin, const int* __restrict__ rowptr,
    const int* __restrict__ col, const unsigned short* __restrict__ Wt,
    const float* __restrict__ bl, unsigned short* __restrict__ hout) {
    __shared__ unsigned short A_sw[64 * 128];  // 16 KB
    int tid = threadIdx.x;
    int w = tid >> 6, lane = tid & 63;
    int q = lane >> 4, t = lane & 15;
    size_t i0 = (size_t)blockIdx.x * 64;

    // ---- phase A: gather ----
    for (int m = 0; m < 16; m++) {
        int node = (int)i0 + w * 16 + m;
        int start = 0, end = 0;
        if (node < N_NODES) {
            start = rowptr[node];
            end = rowptr[node + 1];
        }
        float acc[8];
#pragma unroll
        for (int j = 0; j < 8; j++) acc[j] = 0.f;
        int c = start + q;
        while (c + 4 < end) {
            int ia = col[c], ib = col[c + 4];
            uint4 va = *(const uint4*)(hin + (size_t)ia * DIM + t * 8);
            uint4 vb = *(const uint4*)(hin + (size_t)ib * DIM + t * 8);
            const unsigned int* pa = &va.x;
            const unsigned int* pb = &vb.x;
#pragma unroll
            for (int j = 0; j < 4; j++) {
                acc[2 * j + 0] += bf2f((unsigned short)(pa[j] & 0xFFFF)) +
                                  bf2f((unsigned short)(pb[j] & 0xFFFF));
                acc[2 * j + 1] += bf2f((unsigned short)(pa[j] >> 16)) +
                                  bf2f((unsigned short)(pb[j] >> 16));
            }
            c += 8;
        }
        if (c < end) {
            int ia = col[c];
            uint4 va = *(const uint4*)(hin + (size_t)ia * DIM + t * 8);
            const unsigned int* pa = &va.x;
#pragma unroll
            for (int j = 0; j < 4; j++) {
                acc[2 * j + 0] += bf2f((unsigned short)(pa[j] & 0xFFFF));
                acc[2 * j + 1] += bf2f((unsigned short)(pa[j] >> 16));
            }
        }
#pragma unroll
        for (int j = 0; j < 8; j++) {
            acc[j] += __shfl_xor(acc[j], 16);
            acc[j] += __shfl_xor(acc[j], 32);
        }
        if (q == 0) {
            int deg = end - start;
            float scale = 1.f / (float)(deg > 0 ? deg : 1);
            uint4 o;
            unsigned int* po = &o.x;
#pragma unroll
            for (int j = 0; j < 4; j++)
                po[j] = f2bf(acc[2 * j] * scale) | (f2bf(acc[2 * j + 1] * scale) << 16);
            // frag-swizzled store: rt=w, reader-lane index = m, ks=t>>2, q'=t&3
            *(uint4*)((char*)A_sw + (((w * 4 + (t >> 2)) * 4 + (t & 3)) * 256 + m * 16)) = o;
        }
    }

    // ---- B-fragment preload (global, L2-hot; independent of LDS) ----
    bf16x8 bfrag[2][8];
#pragma unroll
    for (int ct2 = 0; ct2 < 2; ct2++)
#pragma unroll
        for (int ks = 0; ks < 8; ks++)
            bfrag[ct2][ks] =
                *(const bf16x8*)(Wt + (size_t)(w * 32 + ct2 * 16 + t) * 256 + ks * 32 + q * 8);

    __syncthreads();

    // ---- phase C: MFMA ----
    floatx4 acc[4][2];
#pragma unroll
    for (int rt = 0; rt < 4; rt++)
#pragma unroll
        for (int c = 0; c < 2; c++) acc[rt][c] = (floatx4){0.f, 0.f, 0.f, 0.f};

    // issue first global h-frags early (K-block 4)
    bf16x8 hc[4], hn[4];
#pragma unroll
    for (int rt = 0; rt < 4; rt++)
        hc[rt] = *(const bf16x8*)(hin + (i0 + rt * 16 + t) * DIM + q * 8);

    // K-blocks 0..3: A from LDS (agg half)
#pragma unroll
    for (int ks = 0; ks < 4; ks++) {
        bf16x8 af[4];
#pragma unroll
        for (int rt = 0; rt < 4; rt++)
            af[rt] = *(const bf16x8*)((char*)A_sw + (((rt * 4 + ks) * 4 + q) * 256 + t * 16));
#pragma unroll
        for (int rt = 0; rt < 4; rt++) {
            acc[rt][0] = __builtin_amdgcn_mfma_f32_16x16x32_bf16(af[rt], bfrag[0][ks],
                                                                 acc[rt][0], 0, 0, 0);
            acc[rt][1] = __builtin_amdgcn_mfma_f32_16x16x32_bf16(af[rt], bfrag[1][ks],
                                                                 acc[rt][1], 0, 0, 0);
        }
    }
    // K-blocks 4..7: A = h from global (root half), 1-ahead prefetch
#pragma unroll
    for (int ks2 = 0; ks2 < 4; ks2++) {
        if (ks2 < 3) {
#pragma unroll
            for (int rt = 0; rt < 4; rt++)
                hn[rt] = *(const bf16x8*)(hin + (i0 + rt * 16 + t) * DIM + (ks2 + 1) * 32 + q * 8);
        }
#pragma unroll
        for (int rt = 0; rt < 4; rt++) {
            acc[rt][0] = __builtin_amdgcn_mfma_f32_16x16x32_bf16(hc[rt], bfrag[0][4 + ks2],
                                                                 acc[rt][0], 0, 0, 0);
            acc[rt][1] = __builtin_amdgcn_mfma_f32_16x16x32_bf16(hc[rt], bfrag[1][4 + ks2],
                                                                 acc[rt][1], 0, 0, 0);
        }
        if (ks2 < 3) {
#pragma unroll
            for (int rt = 0; rt < 4; rt++) hc[rt] = hn[rt];
        }
    }

    // ---- epilogue ----
    float b0 = bl[w * 32 + t];
    float b1 = bl[w * 32 + 16 + t];
#pragma unroll
    for (int rt = 0; rt < 4; rt++) {
#pragma unroll
        for (int r = 0; r < 4; r++) {
            size_t row = i0 + rt * 16 + q * 4 + r;
            float v0 = acc[rt][0][r] + b0;
            float v1 = acc[rt][1][r] + b1;
            if (RELU) {
                v0 = fmaxf(v0, 0.f);
                v1 = fmaxf(v1, 0.f);
            }
            hout[row * DIM + w * 32 + t] = (unsigned short)f2bf(v0);
            hout[row * DIM + w * 32 + 16 + t] = (unsigned short)f2bf(v1);
        }
    }
}

// ---------------- per-graph mean pool (batch sorted), bf16 input ----------------

__global__ void k_pool(const unsigned short* __restrict__ h, const int* __restrict__ batch,
                       float* __restrict__ pooled, float* __restrict__ gcnt) {
    int tid = threadIdx.x;
    int d = tid & 127, half = tid >> 7;
    int n0 = blockIdx.x * 64 + half * 32;
    if (n0 >= N_NODES) return;
    int nend = n0 + 32;
    if (nend > N_NODES) nend = N_NODES;
    float acc = 0.f;
    int cur = batch[n0];
    int run = 0;
    for (int n = n0; n < nend; n++) {
        int g = batch[n];
        if (g != cur) {
            atomicAdd(&pooled[cur * DIM + d], acc);
            if (d == 0) atomicAdd(&gcnt[cur], (float)run);
            acc = 0.f; run = 0; cur = g;
        }
        acc += bf2f(h[(size_t)n * DIM + d]);
        run++;
    }
    atomicAdd(&pooled[cur * DIM + d], acc);
    if (d == 0) atomicAdd(&gcnt[cur], (float)run);
}

__global__ void k_final(const float* __restrict__ pooled, const float* __restrict__ gcnt,
                        const float* __restrict__ Wlin, const float* __restrict__ blin,
                        float* __restrict__ out) {
    int t = threadIdx.x;  // 128 threads
    int g = t >> 1, o = t & 1;
    float sum = 0.f;
#pragma unroll 8
    for (int k = 0; k < DIM; k++) sum += pooled[g * DIM + k] * Wlin[k * 2 + o];
    float c = gcnt[g];
    out[g * 2 + o] = sum / fmaxf(c, 1.f) + blin[o];
}

// ---------------- launch ----------------

static inline size_t align_up(size_t v, size_t a) { return (v + a - 1) & ~(a - 1); }

extern "C" void kernel_launch(void* const* d_in, const int* in_sizes, int n_in,
                              void* d_out, int out_size, void* d_ws, size_t ws_size,
                              hipStream_t stream) {
    const float* x     = (const float*)d_in[0];
    const int*   ei    = (const int*)d_in[1];
    const int*   src   = ei;
    const int*   dst   = ei + N_EDGES;
    const int*   batch = (const int*)d_in[2];
    const float* Wl1 = (const float*)d_in[3];
    const float* bl1 = (const float*)d_in[4];
    const float* Wr1 = (const float*)d_in[5];
    const float* Wl2 = (const float*)d_in[6];
    const float* bl2 = (const float*)d_in[7];
    const float* Wr2 = (const float*)d_in[8];
    const float* Wl3 = (const float*)d_in[9];
    const float* bl3 = (const float*)d_in[10];
    const float* Wr3 = (const float*)d_in[11];
    const float* Wlin = (const float*)d_in[12];
    const float* blin = (const float*)d_in[13];
    float* out = (float*)d_out;

    char* p = (char*)d_ws;
    size_t off = 0;
    auto carve = [&](size_t bytes) -> void* {
        void* r = p + off;
        off = align_up(off + bytes, 256);
        return r;
    };
    int* rowptr = (int*)carve((N_NODES + 1) * sizeof(int));
    int* bcur   = (int*)carve(NBUCKET * sizeof(int));
    int* bbase  = (int*)carve((NBUCKET + 1) * sizeof(int));
    int* col    = (int*)carve((size_t)N_EDGES * sizeof(int));
    unsigned short* bufA = (unsigned short*)carve((size_t)M_PAD * DIM * 2);
    unsigned short* bufB = (unsigned short*)carve((size_t)M_PAD * DIM * 2);
    unsigned short* bufC = (unsigned short*)carve((size_t)M_PAD * DIM * 2);
    unsigned short* Wt1  = (unsigned short*)carve(256 * 128 * 2);
    unsigned short* Wt2  = (unsigned short*)carve(256 * 128 * 2);
    unsigned short* Wt3  = (unsigned short*)carve(256 * 128 * 2);
    float* pooled = (float*)carve((size_t)NGRAPH * DIM * sizeof(float));
    float* gcnt   = (float*)carve((size_t)NGRAPH * sizeof(float));
    // staging (12.8 MB) aliases bufB: dead after k_bsort; bufB first written
    // by layer 1 later on the same stream.
    unsigned int* staging = (unsigned int*)bufB;

    // ---- CSR build ----
    hipMemsetAsync(bcur, 0, NBUCKET * sizeof(int), stream);
    k_scatter2<<<(N_EDGES + CHUNK - 1) / CHUNK, 1024, 0, stream>>>(src, dst, bcur, staging);
    k_bscan<<<1, 256, 0, stream>>>(bcur, bbase);
    k_bsort<<<NBUCKET, 256, 0, stream>>>(staging, bbase, rowptr, col);

    // ---- conversions ----
    k_convert<<<XBLOCKS + 384, 256, 0, stream>>>(x, bufA, Wl1, Wr1, Wt1, Wl2, Wr2, Wt2,
                                                 Wl3, Wr3, Wt3);

    const int GRID_L = M_PAD / 64;  // 1564

    // ---- fused layers ----
    k_layer<true><<<GRID_L, 256, 0, stream>>>(bufA, rowptr, col, Wt1, bl1, bufB);
    k_layer<true><<<GRID_L, 256, 0, stream>>>(bufB, rowptr, col, Wt2, bl2, bufC);
    k_layer<false><<<GRID_L, 256, 0, stream>>>(bufC, rowptr, col, Wt3, bl3, bufA);

    // ---- pool + final ----
    hipMemsetAsync(pooled, 0, NGRAPH * DIM * sizeof(float) + NGRAPH * sizeof(float), stream);
    k_pool<<<(N_NODES + 63) / 64, 256, 0, stream>>>(bufA, batch, pooled, gcnt);
    k_final<<<1, 128, 0, stream>>>(pooled, gcnt, Wlin, blin, out);
}

// Round 9
// 451.753 us; speedup vs baseline: 1.3367x; 1.3367x over previous
//
#include <hip/hip_runtime.h>

#define N_NODES 100000
#define N_EDGES 1600000
#define DIM 128
#define NGRAPH 64
#define M_PAD 100096   // 782 * 128 = 1564 * 64
#define NBUCKET 782    // ceil(100000 / 128)
#define BCAP 4096      // staging capacity per bucket (mean 2046, sigma ~45)
#define CHUNK 8192     // edges per scatter block
#define XBLOCKS 12500  // N_NODES*DIM/4/256 — x conversion blocks

typedef __attribute__((ext_vector_type(8))) short bf16x8;
typedef __attribute__((ext_vector_type(4))) float floatx4;
typedef __attribute__((ext_vector_type(2))) float floatx2;

static __device__ __forceinline__ unsigned int f2bf(float f) {
    unsigned int u = __builtin_bit_cast(unsigned int, f);
    return (u + 0x7FFFu + ((u >> 16) & 1u)) >> 16;
}
static __device__ __forceinline__ float bf2f(unsigned short b) {
    unsigned int u = ((unsigned int)b) << 16;
    return __builtin_bit_cast(float, u);
}
// 4 floats -> 4 packed fp8 e4m3 (HW RNE)
static __device__ __forceinline__ unsigned int pk_fp8x4(float a, float b, float c, float d) {
    unsigned int r = 0;
    r = __builtin_amdgcn_cvt_pk_fp8_f32(a, b, r, false);
    r = __builtin_amdgcn_cvt_pk_fp8_f32(c, d, r, true);
    return r;
}

// ---------------- fused conversions: x -> bf16 + fp8, 3x W -> transposed bf16 ----------------

__global__ void k_convert(const float* __restrict__ x, unsigned short* __restrict__ xb,
                          unsigned char* __restrict__ x8,
                          const float* __restrict__ Wl1, const float* __restrict__ Wr1,
                          unsigned short* __restrict__ Wt1,
                          const float* __restrict__ Wl2, const float* __restrict__ Wr2,
                          unsigned short* __restrict__ Wt2,
                          const float* __restrict__ Wl3, const float* __restrict__ Wr3,
                          unsigned short* __restrict__ Wt3) {
    int b = blockIdx.x;
    if (b < XBLOCKS) {
        size_t i = (size_t)(b * 256 + threadIdx.x) * 4;
        float4 v = *(const float4*)(x + i);
        uint2 o;
        o.x = f2bf(v.x) | (f2bf(v.y) << 16);
        o.y = f2bf(v.z) | (f2bf(v.w) << 16);
        *(uint2*)(xb + i) = o;
        *(unsigned int*)(x8 + i) = pk_fp8x4(v.x, v.y, v.z, v.w);
    } else {
        int layer = (b - XBLOCKS) >> 7;
        const float* Wl = layer == 0 ? Wl1 : (layer == 1 ? Wl2 : Wl3);
        const float* Wr = layer == 0 ? Wr1 : (layer == 1 ? Wr2 : Wr3);
        unsigned short* Wt = layer == 0 ? Wt1 : (layer == 1 ? Wt2 : Wt3);
        int id = ((b - XBLOCKS) & 127) * 256 + threadIdx.x;  // 0..32767
        int n = id >> 8, k = id & 255;
        float v = (k < 128) ? Wl[k * 128 + n] : Wr[(k - 128) * 128 + n];
        Wt[n * 256 + k] = (unsigned short)f2bf(v);
    }
}

// ---------------- bucketed CSR build (unchanged, round-5-proven) ----------------

__global__ __launch_bounds__(1024) void k_scatter2(const int* __restrict__ src,
                                                   const int* __restrict__ dst,
                                                   int* __restrict__ bcur,
                                                   unsigned int* __restrict__ staging) {
    __shared__ int cnt[NBUCKET];
    __shared__ int gbase[NBUCKET];
    __shared__ int pos[NBUCKET];
    int tid = threadIdx.x;
    int e0 = blockIdx.x * CHUNK;
    for (int i = tid; i < NBUCKET; i += 1024) {
        cnt[i] = 0;
        pos[i] = 0;
    }
    __syncthreads();
    int s[8], d[8];
#pragma unroll
    for (int j = 0; j < 8; j++) {
        int e = e0 + j * 1024 + tid;
        if (e < N_EDGES) {
            s[j] = src[e];
            d[j] = dst[e];
            atomicAdd(&cnt[d[j] >> 7], 1);
        } else {
            d[j] = -1;
        }
    }
    __syncthreads();
    for (int i = tid; i < NBUCKET; i += 1024) {
        int c = cnt[i];
        if (c > 0) gbase[i] = atomicAdd(&bcur[i], c);
    }
    __syncthreads();
#pragma unroll
    for (int j = 0; j < 8; j++) {
        if (d[j] >= 0) {
            int b = d[j] >> 7;
            int gp = gbase[b] + atomicAdd(&pos[b], 1);
            if (gp < BCAP)
                staging[(size_t)b * BCAP + gp] =
                    (unsigned int)s[j] | ((unsigned int)(d[j] & 127) << 25);
        }
    }
}

__global__ void k_bscan(const int* __restrict__ bcnt, int* __restrict__ bbase) {
    __shared__ int s[256];
    int tid = threadIdx.x;
    int v[4];
    int sum = 0;
#pragma unroll
    for (int j = 0; j < 4; j++) {
        int idx = tid * 4 + j;
        v[j] = (idx < NBUCKET) ? bcnt[idx] : 0;
        sum += v[j];
    }
    s[tid] = sum;
    __syncthreads();
    for (int off = 1; off < 256; off <<= 1) {
        int t = (tid >= off) ? s[tid - off] : 0;
        __syncthreads();
        s[tid] += t;
        __syncthreads();
    }
    int run = s[tid] - sum;
#pragma unroll
    for (int j = 0; j < 4; j++) {
        int idx = tid * 4 + j;
        if (idx <= NBUCKET) bbase[idx] = run;
        run += v[j];
    }
}

__global__ __launch_bounds__(256) void k_bsort(const unsigned int* __restrict__ staging,
                                               const int* __restrict__ bbase,
                                               int* __restrict__ rowptr,
                                               int* __restrict__ col) {
    __shared__ unsigned int lpk[BCAP];
    __shared__ int lcol[BCAP];
    __shared__ int loff[129];
    __shared__ int lcur[128];
    int b = blockIdx.x, tid = threadIdx.x;
    int gbase = bbase[b];
    int nE = bbase[b + 1] - gbase;
    if (nE > BCAP) nE = BCAP;
    if (tid < 128) {
        loff[tid] = 0;
        lcur[tid] = 0;
    }
    __syncthreads();
    const unsigned int* sb = staging + (size_t)b * BCAP;
    for (int i = tid; i < nE; i += 256) {
        unsigned int p = sb[i];
        lpk[i] = p;
        atomicAdd(&loff[p >> 25], 1);
    }
    __syncthreads();
    if (tid < 64) {
        int c0 = loff[2 * tid], c1 = loff[2 * tid + 1];
        int ps = c0 + c1;
        for (int off = 1; off < 64; off <<= 1) {
            int t = __shfl_up(ps, off);
            if (tid >= off) ps += t;
        }
        int excl = ps - (c0 + c1);
        loff[2 * tid] = excl;
        loff[2 * tid + 1] = excl + c0;
        if (tid == 63) loff[128] = ps;
    }
    __syncthreads();
    if (tid < 128) {
        int idx = b * 128 + tid;
        if (idx < N_NODES) rowptr[idx] = gbase + loff[tid];
    }
    if (tid == 0 && b == NBUCKET - 1) rowptr[N_NODES] = N_EDGES;
    for (int i = tid; i < nE; i += 256) {
        unsigned int p = lpk[i];
        int d = p >> 25;
        int pos = loff[d] + atomicAdd(&lcur[d], 1);
        lcol[pos] = (int)(p & 0x1FFFFFFu);
    }
    __syncthreads();
    for (int i = tid; i < nE; i += 256) col[gbase + i] = lcol[i];
}

// ---------------- mean aggregation: fp8 in, bf16 out ----------------
// r5-proven structure: 4 nodes/block, one wave/node, quarter q handles rows
// c+q, c+4+q,...; lane t covers dims t*8..t*8+7 (8 fp8 = 8B loads); 2 rows in
// flight; fp32 accumulate via HW fp8->f32 cvt; shfl_xor reduce.

__global__ __launch_bounds__(256) void k_gather_f8(
    const unsigned char* __restrict__ hin8, const int* __restrict__ rowptr,
    const int* __restrict__ col, unsigned short* __restrict__ agg) {
    int lane = threadIdx.x & 63;
    int node = blockIdx.x * 4 + (threadIdx.x >> 6);
    int q = lane >> 4, t = lane & 15;
    int start = rowptr[node], end = rowptr[node + 1];
    float acc[8];
#pragma unroll
    for (int j = 0; j < 8; j++) acc[j] = 0.f;

    int c = start + q;
    while (c + 4 < end) {
        int ia = col[c], ib = col[c + 4];
        uint2 va = *(const uint2*)(hin8 + (size_t)ia * DIM + t * 8);
        uint2 vb = *(const uint2*)(hin8 + (size_t)ib * DIM + t * 8);
        floatx2 f;
        f = __builtin_amdgcn_cvt_pk_f32_fp8(va.x, false); acc[0] += f.x; acc[1] += f.y;
        f = __builtin_amdgcn_cvt_pk_f32_fp8(va.x, true);  acc[2] += f.x; acc[3] += f.y;
        f = __builtin_amdgcn_cvt_pk_f32_fp8(va.y, false); acc[4] += f.x; acc[5] += f.y;
        f = __builtin_amdgcn_cvt_pk_f32_fp8(va.y, true);  acc[6] += f.x; acc[7] += f.y;
        f = __builtin_amdgcn_cvt_pk_f32_fp8(vb.x, false); acc[0] += f.x; acc[1] += f.y;
        f = __builtin_amdgcn_cvt_pk_f32_fp8(vb.x, true);  acc[2] += f.x; acc[3] += f.y;
        f = __builtin_amdgcn_cvt_pk_f32_fp8(vb.y, false); acc[4] += f.x; acc[5] += f.y;
        f = __builtin_amdgcn_cvt_pk_f32_fp8(vb.y, true);  acc[6] += f.x; acc[7] += f.y;
        c += 8;
    }
    if (c < end) {
        int ia = col[c];
        uint2 va = *(const uint2*)(hin8 + (size_t)ia * DIM + t * 8);
        floatx2 f;
        f = __builtin_amdgcn_cvt_pk_f32_fp8(va.x, false); acc[0] += f.x; acc[1] += f.y;
        f = __builtin_amdgcn_cvt_pk_f32_fp8(va.x, true);  acc[2] += f.x; acc[3] += f.y;
        f = __builtin_amdgcn_cvt_pk_f32_fp8(va.y, false); acc[4] += f.x; acc[5] += f.y;
        f = __builtin_amdgcn_cvt_pk_f32_fp8(va.y, true);  acc[6] += f.x; acc[7] += f.y;
    }
#pragma unroll
    for (int j = 0; j < 8; j++) {
        acc[j] += __shfl_xor(acc[j], 16);
        acc[j] += __shfl_xor(acc[j], 32);
    }
    if (q == 0) {
        int deg = end - start;
        float scale = 1.f / (float)(deg > 0 ? deg : 1);
        uint4 o;
        unsigned int* po = &o.x;
#pragma unroll
        for (int j = 0; j < 4; j++)
            po[j] = f2bf(acc[2 * j] * scale) | (f2bf(acc[2 * j + 1] * scale) << 16);
        *(uint4*)(agg + (size_t)node * DIM + t * 8) = o;
    }
}

// ---------------- fused linear via MFMA (r7 structure + fp8 dual-store) ----------------

template <bool RELU, bool STORE8>
__global__ __launch_bounds__(256) void k_linear_mfma(
    const unsigned short* __restrict__ aggb, const unsigned short* __restrict__ hb,
    const unsigned short* __restrict__ Wt, const float* __restrict__ bl,
    unsigned short* __restrict__ hout, unsigned char* __restrict__ hout8) {
    int tid = threadIdx.x;
    int w = tid >> 6, lane = tid & 63;
    int t = lane & 15, q = lane >> 4;
    size_t i0 = (size_t)blockIdx.x * 64;

    bf16x8 bfrag[2][8];
#pragma unroll
    for (int ct2 = 0; ct2 < 2; ct2++)
#pragma unroll
        for (int ks = 0; ks < 8; ks++)
            bfrag[ct2][ks] =
                *(const bf16x8*)(Wt + (size_t)(w * 32 + ct2 * 16 + t) * 256 + ks * 32 + q * 8);

    floatx4 acc[4][2];
#pragma unroll
    for (int rt = 0; rt < 4; rt++)
#pragma unroll
        for (int c = 0; c < 2; c++) acc[rt][c] = (floatx4){0.f, 0.f, 0.f, 0.f};

    bf16x8 a_cur[4];
#pragma unroll
    for (int rt = 0; rt < 4; rt++)
        a_cur[rt] = *(const bf16x8*)(aggb + (i0 + rt * 16 + t) * DIM + q * 8);

#pragma unroll
    for (int ks = 0; ks < 8; ks++) {
        bf16x8 a_nxt[4];
        if (ks < 7) {
            const unsigned short* base = ((ks + 1) < 4) ? aggb : hb;
            int ko = ((ks + 1) & 3) * 32;
#pragma unroll
            for (int rt = 0; rt < 4; rt++)
                a_nxt[rt] = *(const bf16x8*)(base + (i0 + rt * 16 + t) * DIM + ko + q * 8);
        }
#pragma unroll
        for (int rt = 0; rt < 4; rt++) {
            acc[rt][0] = __builtin_amdgcn_mfma_f32_16x16x32_bf16(a_cur[rt], bfrag[0][ks],
                                                                 acc[rt][0], 0, 0, 0);
            acc[rt][1] = __builtin_amdgcn_mfma_f32_16x16x32_bf16(a_cur[rt], bfrag[1][ks],
                                                                 acc[rt][1], 0, 0, 0);
        }
        if (ks < 7) {
#pragma unroll
            for (int rt = 0; rt < 4; rt++) a_cur[rt] = a_nxt[rt];
        }
    }

    float b0 = bl[w * 32 + t];
    float b1 = bl[w * 32 + 16 + t];
#pragma unroll
    for (int rt = 0; rt < 4; rt++) {
#pragma unroll
        for (int r = 0; r < 4; r++) {
            size_t row = i0 + rt * 16 + q * 4 + r;
            float v0 = acc[rt][0][r] + b0;
            float v1 = acc[rt][1][r] + b1;
            if (RELU) {
                v0 = fmaxf(v0, 0.f);
                v1 = fmaxf(v1, 0.f);
            }
            hout[row * DIM + w * 32 + t] = (unsigned short)f2bf(v0);
            hout[row * DIM + w * 32 + 16 + t] = (unsigned short)f2bf(v1);
            if (STORE8) {
                unsigned int pk = __builtin_amdgcn_cvt_pk_fp8_f32(v0, v1, 0u, false);
                hout8[row * DIM + w * 32 + t] = (unsigned char)(pk & 0xFF);
                hout8[row * DIM + w * 32 + 16 + t] = (unsigned char)((pk >> 8) & 0xFF);
            }
        }
    }
}

// ---------------- per-graph mean pool (batch sorted), bf16 input ----------------

__global__ void k_pool(const unsigned short* __restrict__ h, const int* __restrict__ batch,
                       float* __restrict__ pooled, float* __restrict__ gcnt) {
    int tid = threadIdx.x;
    int d = tid & 127, half = tid >> 7;
    int n0 = blockIdx.x * 64 + half * 32;
    if (n0 >= N_NODES) return;
    int nend = n0 + 32;
    if (nend > N_NODES) nend = N_NODES;
    float acc = 0.f;
    int cur = batch[n0];
    int run = 0;
    for (int n = n0; n < nend; n++) {
        int g = batch[n];
        if (g != cur) {
            atomicAdd(&pooled[cur * DIM + d], acc);
            if (d == 0) atomicAdd(&gcnt[cur], (float)run);
            acc = 0.f; run = 0; cur = g;
        }
        acc += bf2f(h[(size_t)n * DIM + d]);
        run++;
    }
    atomicAdd(&pooled[cur * DIM + d], acc);
    if (d == 0) atomicAdd(&gcnt[cur], (float)run);
}

__global__ void k_final(const float* __restrict__ pooled, const float* __restrict__ gcnt,
                        const float* __restrict__ Wlin, const float* __restrict__ blin,
                        float* __restrict__ out) {
    int t = threadIdx.x;  // 128 threads
    int g = t >> 1, o = t & 1;
    float sum = 0.f;
#pragma unroll 8
    for (int k = 0; k < DIM; k++) sum += pooled[g * DIM + k] * Wlin[k * 2 + o];
    float c = gcnt[g];
    out[g * 2 + o] = sum / fmaxf(c, 1.f) + blin[o];
}

// ---------------- launch ----------------

static inline size_t align_up(size_t v, size_t a) { return (v + a - 1) & ~(a - 1); }

extern "C" void kernel_launch(void* const* d_in, const int* in_sizes, int n_in,
                              void* d_out, int out_size, void* d_ws, size_t ws_size,
                              hipStream_t stream) {
    const float* x     = (const float*)d_in[0];
    const int*   ei    = (const int*)d_in[1];
    const int*   src   = ei;
    const int*   dst   = ei + N_EDGES;
    const int*   batch = (const int*)d_in[2];
    const float* Wl1 = (const float*)d_in[3];
    const float* bl1 = (const float*)d_in[4];
    const float* Wr1 = (const float*)d_in[5];
    const float* Wl2 = (const float*)d_in[6];
    const float* bl2 = (const float*)d_in[7];
    const float* Wr2 = (const float*)d_in[8];
    const float* Wl3 = (const float*)d_in[9];
    const float* bl3 = (const float*)d_in[10];
    const float* Wr3 = (const float*)d_in[11];
    const float* Wlin = (const float*)d_in[12];
    const float* blin = (const float*)d_in[13];
    float* out = (float*)d_out;

    char* p = (char*)d_ws;
    size_t off = 0;
    auto carve = [&](size_t bytes) -> void* {
        void* r = p + off;
        off = align_up(off + bytes, 256);
        return r;
    };
    int* rowptr = (int*)carve((N_NODES + 1) * sizeof(int));
    int* bcur   = (int*)carve(NBUCKET * sizeof(int));
    int* bbase  = (int*)carve((NBUCKET + 1) * sizeof(int));
    int* col    = (int*)carve((size_t)N_EDGES * sizeof(int));
    unsigned short* bufA = (unsigned short*)carve((size_t)M_PAD * DIM * 2);
    unsigned short* bufB = (unsigned short*)carve((size_t)M_PAD * DIM * 2);
    unsigned short* bufC = (unsigned short*)carve((size_t)M_PAD * DIM * 2);
    unsigned short* agg  = (unsigned short*)carve((size_t)M_PAD * DIM * 2);
    unsigned char*  bufA8 = (unsigned char*)carve((size_t)M_PAD * DIM);
    unsigned char*  bufB8 = (unsigned char*)carve((size_t)M_PAD * DIM);
    unsigned char*  bufC8 = (unsigned char*)carve((size_t)M_PAD * DIM);
    unsigned short* Wt1  = (unsigned short*)carve(256 * 128 * 2);
    unsigned short* Wt2  = (unsigned short*)carve(256 * 128 * 2);
    unsigned short* Wt3  = (unsigned short*)carve(256 * 128 * 2);
    float* pooled = (float*)carve((size_t)NGRAPH * DIM * sizeof(float));
    float* gcnt   = (float*)carve((size_t)NGRAPH * sizeof(float));
    // staging (12.8 MB) aliases bufB: dead after k_bsort; bufB first written
    // by layer 1's linear later on the same stream.
    unsigned int* staging = (unsigned int*)bufB;

    // ---- CSR build ----
    hipMemsetAsync(bcur, 0, NBUCKET * sizeof(int), stream);
    k_scatter2<<<(N_EDGES + CHUNK - 1) / CHUNK, 1024, 0, stream>>>(src, dst, bcur, staging);
    k_bscan<<<1, 256, 0, stream>>>(bcur, bbase);
    k_bsort<<<NBUCKET, 256, 0, stream>>>(staging, bbase, rowptr, col);

    // ---- conversions ----
    k_convert<<<XBLOCKS + 384, 256, 0, stream>>>(x, bufA, bufA8, Wl1, Wr1, Wt1,
                                                 Wl2, Wr2, Wt2, Wl3, Wr3, Wt3);

    const int GRID_G = N_NODES / 4;  // 25000
    const int GRID_L = M_PAD / 64;   // 1564

    // ---- layer 1 ----
    k_gather_f8<<<GRID_G, 256, 0, stream>>>(bufA8, rowptr, col, agg);
    k_linear_mfma<true, true><<<GRID_L, 256, 0, stream>>>(agg, bufA, Wt1, bl1, bufB, bufB8);
    // ---- layer 2 ----
    k_gather_f8<<<GRID_G, 256, 0, stream>>>(bufB8, rowptr, col, agg);
    k_linear_mfma<true, true><<<GRID_L, 256, 0, stream>>>(agg, bufB, Wt2, bl2, bufC, bufC8);
    // ---- layer 3 ----
    k_gather_f8<<<GRID_G, 256, 0, stream>>>(bufC8, rowptr, col, agg);
    k_linear_mfma<false, false><<<GRID_L, 256, 0, stream>>>(agg, bufC, Wt3, bl3, bufA, bufA8);

    // ---- pool + final ----
    hipMemsetAsync(pooled, 0, NGRAPH * DIM * sizeof(float) + NGRAPH * sizeof(float), stream);
    k_pool<<<(N_NODES + 63) / 64, 256, 0, stream>>>(bufA, batch, pooled, gcnt);
    k_final<<<1, 128, 0, stream>>>(pooled, gcnt, Wlin, blin, out);
}

// Round 10
// 397.994 us; speedup vs baseline: 1.5172x; 1.1351x over previous
//
#include <hip/hip_runtime.h>

#define N_NODES 100000
#define N_EDGES 1600000
#define DIM 128
#define NGRAPH 64
#define M_PAD 100096   // 782 * 128 = 1564 * 64
#define NBUCKET 782    // ceil(100000 / 128)
#define BCAP 4096      // staging capacity per bucket (mean 2046, sigma ~45)
#define CHUNK 8192     // edges per scatter block
#define SCAT_B 196     // scatter blocks in k_prep
#define XCV_B 3125     // x-convert blocks in k_prep (12.8M floats / 4096)
#define WCV_B 24       // W-convert blocks in k_prep (98304 / 4096)

typedef __attribute__((ext_vector_type(8))) short bf16x8;
typedef __attribute__((ext_vector_type(4))) float floatx4;
typedef __attribute__((ext_vector_type(2))) float floatx2;

static __device__ __forceinline__ unsigned int f2bf(float f) {
    unsigned int u = __builtin_bit_cast(unsigned int, f);
    return (u + 0x7FFFu + ((u >> 16) & 1u)) >> 16;
}
static __device__ __forceinline__ float bf2f(unsigned short b) {
    unsigned int u = ((unsigned int)b) << 16;
    return __builtin_bit_cast(float, u);
}
static __device__ __forceinline__ unsigned int pk_fp8x4(float a, float b, float c, float d) {
    unsigned int r = 0;
    r = __builtin_amdgcn_cvt_pk_fp8_f32(a, b, r, false);
    r = __builtin_amdgcn_cvt_pk_fp8_f32(c, d, r, true);
    return r;
}
// async global->LDS DMA, 16B per lane; lds dest = (wave-uniform) base + lane*16
static __device__ __forceinline__ void gld_lds16(const void* g, void* l) {
    __builtin_amdgcn_global_load_lds(
        (const __attribute__((address_space(1))) unsigned int*)g,
        (__attribute__((address_space(3))) unsigned int*)l, 16, 0, 0);
}

// ---------------- fused prep: edge scatter + x->bf16+fp8 + 3x W transpose ----------------
// blocks [0,SCAT_B): bucketed edge scatter (LDS histogram + chunk reservation)
// blocks [SCAT_B, SCAT_B+XCV_B): x conversion, 4096 floats each (exact cover)
// blocks [.., +WCV_B): weight transpose+convert, 4096 elements each (exact)

__global__ __launch_bounds__(1024) void k_prep(
    const int* __restrict__ src, const int* __restrict__ dst,
    int* __restrict__ bcur, unsigned int* __restrict__ staging,
    const float* __restrict__ x, unsigned short* __restrict__ xb,
    unsigned char* __restrict__ x8,
    const float* __restrict__ Wl1, const float* __restrict__ Wr1,
    unsigned short* __restrict__ Wt1,
    const float* __restrict__ Wl2, const float* __restrict__ Wr2,
    unsigned short* __restrict__ Wt2,
    const float* __restrict__ Wl3, const float* __restrict__ Wr3,
    unsigned short* __restrict__ Wt3) {
    int b = blockIdx.x;
    int tid = threadIdx.x;
    if (b < SCAT_B) {
        __shared__ int cnt[NBUCKET];
        __shared__ int gbase[NBUCKET];
        __shared__ int pos[NBUCKET];
        int e0 = b * CHUNK;
        for (int i = tid; i < NBUCKET; i += 1024) {
            cnt[i] = 0;
            pos[i] = 0;
        }
        __syncthreads();
        int s[8], d[8];
#pragma unroll
        for (int j = 0; j < 8; j++) {
            int e = e0 + j * 1024 + tid;
            if (e < N_EDGES) {
                s[j] = src[e];
                d[j] = dst[e];
                atomicAdd(&cnt[d[j] >> 7], 1);
            } else {
                d[j] = -1;
            }
        }
        __syncthreads();
        for (int i = tid; i < NBUCKET; i += 1024) {
            int c = cnt[i];
            if (c > 0) gbase[i] = atomicAdd(&bcur[i], c);
        }
        __syncthreads();
#pragma unroll
        for (int j = 0; j < 8; j++) {
            if (d[j] >= 0) {
                int bk = d[j] >> 7;
                int gp = gbase[bk] + atomicAdd(&pos[bk], 1);
                if (gp < BCAP)
                    staging[(size_t)bk * BCAP + gp] =
                        (unsigned int)s[j] | ((unsigned int)(d[j] & 127) << 25);
            }
        }
    } else if (b < SCAT_B + XCV_B) {
        size_t i = ((size_t)(b - SCAT_B) * 1024 + tid) * 4;
        float4 v = *(const float4*)(x + i);
        uint2 o;
        o.x = f2bf(v.x) | (f2bf(v.y) << 16);
        o.y = f2bf(v.z) | (f2bf(v.w) << 16);
        *(uint2*)(xb + i) = o;
        *(unsigned int*)(x8 + i) = pk_fp8x4(v.x, v.y, v.z, v.w);
    } else {
        int base = (b - SCAT_B - XCV_B) * 4096 + tid * 4;
#pragma unroll
        for (int j = 0; j < 4; j++) {
            int id = base + j;                 // 0..98303
            int layer = id >> 15;
            int rem = id & 32767;
            int n = rem >> 8, k = rem & 255;
            const float* Wl = layer == 0 ? Wl1 : (layer == 1 ? Wl2 : Wl3);
            const float* Wr = layer == 0 ? Wr1 : (layer == 1 ? Wr2 : Wr3);
            unsigned short* Wt = layer == 0 ? Wt1 : (layer == 1 ? Wt2 : Wt3);
            float v = (k < 128) ? Wl[k * 128 + n] : Wr[(k - 128) * 128 + n];
            Wt[n * 256 + k] = (unsigned short)f2bf(v);
        }
    }
}

// ---------------- CSR finish: bucket scan + per-bucket counting sort ----------------

__global__ void k_bscan(const int* __restrict__ bcnt, int* __restrict__ bbase) {
    __shared__ int s[256];
    int tid = threadIdx.x;
    int v[4];
    int sum = 0;
#pragma unroll
    for (int j = 0; j < 4; j++) {
        int idx = tid * 4 + j;
        v[j] = (idx < NBUCKET) ? bcnt[idx] : 0;
        sum += v[j];
    }
    s[tid] = sum;
    __syncthreads();
    for (int off = 1; off < 256; off <<= 1) {
        int t = (tid >= off) ? s[tid - off] : 0;
        __syncthreads();
        s[tid] += t;
        __syncthreads();
    }
    int run = s[tid] - sum;
#pragma unroll
    for (int j = 0; j < 4; j++) {
        int idx = tid * 4 + j;
        if (idx <= NBUCKET) bbase[idx] = run;
        run += v[j];
    }
}

__global__ __launch_bounds__(256) void k_bsort(const unsigned int* __restrict__ staging,
                                               const int* __restrict__ bbase,
                                               int* __restrict__ rowptr,
                                               int* __restrict__ col) {
    __shared__ unsigned int lpk[BCAP];
    __shared__ int lcol[BCAP];
    __shared__ int loff[129];
    __shared__ int lcur[128];
    int b = blockIdx.x, tid = threadIdx.x;
    int gbase = bbase[b];
    int nE = bbase[b + 1] - gbase;
    if (nE > BCAP) nE = BCAP;
    if (tid < 128) {
        loff[tid] = 0;
        lcur[tid] = 0;
    }
    __syncthreads();
    const unsigned int* sb = staging + (size_t)b * BCAP;
    for (int i = tid; i < nE; i += 256) {
        unsigned int p = sb[i];
        lpk[i] = p;
        atomicAdd(&loff[p >> 25], 1);
    }
    __syncthreads();
    if (tid < 64) {
        int c0 = loff[2 * tid], c1 = loff[2 * tid + 1];
        int ps = c0 + c1;
        for (int off = 1; off < 64; off <<= 1) {
            int t = __shfl_up(ps, off);
            if (tid >= off) ps += t;
        }
        int excl = ps - (c0 + c1);
        loff[2 * tid] = excl;
        loff[2 * tid + 1] = excl + c0;
        if (tid == 63) loff[128] = ps;
    }
    __syncthreads();
    if (tid < 128) {
        int idx = b * 128 + tid;
        if (idx < N_NODES) rowptr[idx] = gbase + loff[tid];
    }
    if (tid == 0 && b == NBUCKET - 1) rowptr[N_NODES] = N_EDGES;
    for (int i = tid; i < nE; i += 256) {
        unsigned int p = lpk[i];
        int d = p >> 25;
        int pos = loff[d] + atomicAdd(&lcur[d], 1);
        lcol[pos] = (int)(p & 0x1FFFFFFu);
    }
    __syncthreads();
    for (int i = tid; i < nE; i += 256) col[gbase + i] = lcol[i];
}

// ---------------- mean aggregation: fp8 in, bf16 out (pk_add accumulate) ----------------

__global__ __launch_bounds__(256) void k_gather_f8(
    const unsigned char* __restrict__ hin8, const int* __restrict__ rowptr,
    const int* __restrict__ col, unsigned short* __restrict__ agg) {
    int lane = threadIdx.x & 63;
    int node = blockIdx.x * 4 + (threadIdx.x >> 6);
    int q = lane >> 4, t = lane & 15;
    int start = rowptr[node], end = rowptr[node + 1];
    floatx2 a2[4];
#pragma unroll
    for (int j = 0; j < 4; j++) a2[j] = (floatx2){0.f, 0.f};

    int c = start + q;
    while (c + 4 < end) {
        int ia = col[c], ib = col[c + 4];
        uint2 va = *(const uint2*)(hin8 + (size_t)ia * DIM + t * 8);
        uint2 vb = *(const uint2*)(hin8 + (size_t)ib * DIM + t * 8);
        a2[0] += __builtin_amdgcn_cvt_pk_f32_fp8(va.x, false);
        a2[1] += __builtin_amdgcn_cvt_pk_f32_fp8(va.x, true);
        a2[2] += __builtin_amdgcn_cvt_pk_f32_fp8(va.y, false);
        a2[3] += __builtin_amdgcn_cvt_pk_f32_fp8(va.y, true);
        a2[0] += __builtin_amdgcn_cvt_pk_f32_fp8(vb.x, false);
        a2[1] += __builtin_amdgcn_cvt_pk_f32_fp8(vb.x, true);
        a2[2] += __builtin_amdgcn_cvt_pk_f32_fp8(vb.y, false);
        a2[3] += __builtin_amdgcn_cvt_pk_f32_fp8(vb.y, true);
        c += 8;
    }
    if (c < end) {
        int ia = col[c];
        uint2 va = *(const uint2*)(hin8 + (size_t)ia * DIM + t * 8);
        a2[0] += __builtin_amdgcn_cvt_pk_f32_fp8(va.x, false);
        a2[1] += __builtin_amdgcn_cvt_pk_f32_fp8(va.x, true);
        a2[2] += __builtin_amdgcn_cvt_pk_f32_fp8(va.y, false);
        a2[3] += __builtin_amdgcn_cvt_pk_f32_fp8(va.y, true);
    }
    float acc[8];
#pragma unroll
    for (int j = 0; j < 4; j++) {
        acc[2 * j] = a2[j].x;
        acc[2 * j + 1] = a2[j].y;
    }
#pragma unroll
    for (int j = 0; j < 8; j++) {
        acc[j] += __shfl_xor(acc[j], 16);
        acc[j] += __shfl_xor(acc[j], 32);
    }
    if (q == 0) {
        int deg = end - start;
        float scale = 1.f / (float)(deg > 0 ? deg : 1);
        uint4 o;
        unsigned int* po = &o.x;
#pragma unroll
        for (int j = 0; j < 4; j++)
            po[j] = f2bf(acc[2 * j] * scale) | (f2bf(acc[2 * j + 1] * scale) << 16);
        *(uint4*)(agg + (size_t)node * DIM + t * 8) = o;
    }
}

// ---------------- fused linear via MFMA, async-LDS-staged A ----------------
// Block = 256 thr = 4 waves; tile 64 rows x 128 cols. Both A-halves (agg rows,
// h rows: 16 KB each) staged to LDS via global_load_lds width=16, XOR-swizzled:
// LDS slot(row, s) holds 16B chunk c = s ^ (row & 15) of that row. Reader lane
// (t,q) for k-block ks fetches s = (ks*4+q) ^ t -> banks spread 2-way (free).
// B-frags (Wt, L2-hot) load to VGPRs during the staging flight. K-loop runs
// entirely from LDS/registers. Epilogue: bias+ReLU, bf16 + optional fp8 store.

template <bool RELU, bool STORE8>
__global__ __launch_bounds__(256) void k_linear_mfma(
    const unsigned short* __restrict__ aggb, const unsigned short* __restrict__ hb,
    const unsigned short* __restrict__ Wt, const float* __restrict__ bl,
    unsigned short* __restrict__ hout, unsigned char* __restrict__ hout8) {
    __shared__ unsigned char Alds[32768];  // [0,16K): agg tile, [16K,32K): h tile
    int tid = threadIdx.x;
    int w = tid >> 6, lane = tid & 63;
    int t = lane & 15, q = lane >> 4;
    size_t i0 = (size_t)blockIdx.x * 64;

    // ---- async staging: wave w stages rows w*16..w*16+15 of both tiles ----
#pragma unroll
    for (int k = 0; k < 4; k++) {
        int rowc = w * 16 + k * 4 + (lane >> 4);   // rows covered by this call
        int s = lane & 15;
        int c = s ^ (rowc & 15);
        const unsigned short* ga = aggb + (i0 + rowc) * DIM + c * 8;
        const unsigned short* gh = hb + (i0 + rowc) * DIM + c * 8;
        gld_lds16(ga, Alds + (w * 16 + k * 4) * 256);
        gld_lds16(gh, Alds + 16384 + (w * 16 + k * 4) * 256);
    }

    // ---- B-fragment loads overlap the staging DMAs ----
    bf16x8 bfrag[2][8];
#pragma unroll
    for (int ct2 = 0; ct2 < 2; ct2++)
#pragma unroll
        for (int ks = 0; ks < 8; ks++)
            bfrag[ct2][ks] =
                *(const bf16x8*)(Wt + (size_t)(w * 32 + ct2 * 16 + t) * 256 + ks * 32 + q * 8);

    floatx4 acc[4][2];
#pragma unroll
    for (int rt = 0; rt < 4; rt++)
#pragma unroll
        for (int c = 0; c < 2; c++) acc[rt][c] = (floatx4){0.f, 0.f, 0.f, 0.f};

    __syncthreads();  // drains vmcnt incl. global_load_lds

    // ---- K-loop from LDS ----
#pragma unroll
    for (int ks = 0; ks < 8; ks++) {
        int half = (ks < 4) ? 0 : 16384;
        int kk = ks & 3;
        int s = ((kk * 4 + q) ^ t) * 16;
        bf16x8 af[4];
#pragma unroll
        for (int rt = 0; rt < 4; rt++)
            af[rt] = *(const bf16x8*)(Alds + half + (rt * 16 + t) * 256 + s);
#pragma unroll
        for (int rt = 0; rt < 4; rt++) {
            acc[rt][0] = __builtin_amdgcn_mfma_f32_16x16x32_bf16(af[rt], bfrag[0][ks],
                                                                 acc[rt][0], 0, 0, 0);
            acc[rt][1] = __builtin_amdgcn_mfma_f32_16x16x32_bf16(af[rt], bfrag[1][ks],
                                                                 acc[rt][1], 0, 0, 0);
        }
    }

    // ---- epilogue ----
    float b0 = bl[w * 32 + t];
    float b1 = bl[w * 32 + 16 + t];
#pragma unroll
    for (int rt = 0; rt < 4; rt++) {
#pragma unroll
        for (int r = 0; r < 4; r++) {
            size_t row = i0 + rt * 16 + q * 4 + r;
            float v0 = acc[rt][0][r] + b0;
            float v1 = acc[rt][1][r] + b1;
            if (RELU) {
                v0 = fmaxf(v0, 0.f);
                v1 = fmaxf(v1, 0.f);
            }
            hout[row * DIM + w * 32 + t] = (unsigned short)f2bf(v0);
            hout[row * DIM + w * 32 + 16 + t] = (unsigned short)f2bf(v1);
            if (STORE8) {
                unsigned int pk = __builtin_amdgcn_cvt_pk_fp8_f32(v0, v1, 0u, false);
                hout8[row * DIM + w * 32 + t] = (unsigned char)(pk & 0xFF);
                hout8[row * DIM + w * 32 + 16 + t] = (unsigned char)((pk >> 8) & 0xFF);
            }
        }
    }
}

// ---------------- per-graph mean pool (batch sorted), bf16 input ----------------

__global__ void k_pool(const unsigned short* __restrict__ h, const int* __restrict__ batch,
                       float* __restrict__ pooled, float* __restrict__ gcnt) {
    int tid = threadIdx.x;
    int d = tid & 127, half = tid >> 7;
    int n0 = blockIdx.x * 64 + half * 32;
    if (n0 >= N_NODES) return;
    int nend = n0 + 32;
    if (nend > N_NODES) nend = N_NODES;
    float acc = 0.f;
    int cur = batch[n0];
    int run = 0;
    for (int n = n0; n < nend; n++) {
        int g = batch[n];
        if (g != cur) {
            atomicAdd(&pooled[cur * DIM + d], acc);
            if (d == 0) atomicAdd(&gcnt[cur], (float)run);
            acc = 0.f; run = 0; cur = g;
        }
        acc += bf2f(h[(size_t)n * DIM + d]);
        run++;
    }
    atomicAdd(&pooled[cur * DIM + d], acc);
    if (d == 0) atomicAdd(&gcnt[cur], (float)run);
}

__global__ void k_final(const float* __restrict__ pooled, const float* __restrict__ gcnt,
                        const float* __restrict__ Wlin, const float* __restrict__ blin,
                        float* __restrict__ out) {
    int t = threadIdx.x;  // 128 threads
    int g = t >> 1, o = t & 1;
    float sum = 0.f;
#pragma unroll 8
    for (int k = 0; k < DIM; k++) sum += pooled[g * DIM + k] * Wlin[k * 2 + o];
    float c = gcnt[g];
    out[g * 2 + o] = sum / fmaxf(c, 1.f) + blin[o];
}

// ---------------- launch ----------------

static inline size_t align_up(size_t v, size_t a) { return (v + a - 1) & ~(a - 1); }

extern "C" void kernel_launch(void* const* d_in, const int* in_sizes, int n_in,
                              void* d_out, int out_size, void* d_ws, size_t ws_size,
                              hipStream_t stream) {
    const float* x     = (const float*)d_in[0];
    const int*   ei    = (const int*)d_in[1];
    const int*   src   = ei;
    const int*   dst   = ei + N_EDGES;
    const int*   batch = (const int*)d_in[2];
    const float* Wl1 = (const float*)d_in[3];
    const float* bl1 = (const float*)d_in[4];
    const float* Wr1 = (const float*)d_in[5];
    const float* Wl2 = (const float*)d_in[6];
    const float* bl2 = (const float*)d_in[7];
    const float* Wr2 = (const float*)d_in[8];
    const float* Wl3 = (const float*)d_in[9];
    const float* bl3 = (const float*)d_in[10];
    const float* Wr3 = (const float*)d_in[11];
    const float* Wlin = (const float*)d_in[12];
    const float* blin = (const float*)d_in[13];
    float* out = (float*)d_out;

    char* p = (char*)d_ws;
    size_t off = 0;
    auto carve = [&](size_t bytes) -> void* {
        void* r = p + off;
        off = align_up(off + bytes, 256);
        return r;
    };
    int* rowptr = (int*)carve((N_NODES + 1) * sizeof(int));
    int* bcur   = (int*)carve(NBUCKET * sizeof(int));
    int* bbase  = (int*)carve((NBUCKET + 1) * sizeof(int));
    int* col    = (int*)carve((size_t)N_EDGES * sizeof(int));
    unsigned short* bufA = (unsigned short*)carve((size_t)M_PAD * DIM * 2);
    unsigned short* bufB = (unsigned short*)carve((size_t)M_PAD * DIM * 2);
    unsigned short* bufC = (unsigned short*)carve((size_t)M_PAD * DIM * 2);
    unsigned short* agg  = (unsigned short*)carve((size_t)M_PAD * DIM * 2);
    unsigned char*  bufA8 = (unsigned char*)carve((size_t)M_PAD * DIM);
    unsigned char*  bufB8 = (unsigned char*)carve((size_t)M_PAD * DIM);
    unsigned char*  bufC8 = (unsigned char*)carve((size_t)M_PAD * DIM);
    unsigned short* Wt1  = (unsigned short*)carve(256 * 128 * 2);
    unsigned short* Wt2  = (unsigned short*)carve(256 * 128 * 2);
    unsigned short* Wt3  = (unsigned short*)carve(256 * 128 * 2);
    float* pooled = (float*)carve((size_t)NGRAPH * DIM * sizeof(float));
    float* gcnt   = (float*)carve((size_t)NGRAPH * sizeof(float));
    // staging (12.8 MB) aliases bufB: dead after k_bsort; bufB first written
    // by layer 1's linear later on the same stream.
    unsigned int* staging = (unsigned int*)bufB;

    // ---- prep: edge scatter + all dtype conversions in one dispatch ----
    hipMemsetAsync(bcur, 0, NBUCKET * sizeof(int), stream);
    k_prep<<<SCAT_B + XCV_B + WCV_B, 1024, 0, stream>>>(
        src, dst, bcur, staging, x, bufA, bufA8,
        Wl1, Wr1, Wt1, Wl2, Wr2, Wt2, Wl3, Wr3, Wt3);
    k_bscan<<<1, 256, 0, stream>>>(bcur, bbase);
    k_bsort<<<NBUCKET, 256, 0, stream>>>(staging, bbase, rowptr, col);

    const int GRID_G = N_NODES / 4;  // 25000
    const int GRID_L = M_PAD / 64;   // 1564

    // ---- layer 1 ----
    k_gather_f8<<<GRID_G, 256, 0, stream>>>(bufA8, rowptr, col, agg);
    k_linear_mfma<true, true><<<GRID_L, 256, 0, stream>>>(agg, bufA, Wt1, bl1, bufB, bufB8);
    // ---- layer 2 ----
    k_gather_f8<<<GRID_G, 256, 0, stream>>>(bufB8, rowptr, col, agg);
    k_linear_mfma<true, true><<<GRID_L, 256, 0, stream>>>(agg, bufB, Wt2, bl2, bufC, bufC8);
    // ---- layer 3 ----
    k_gather_f8<<<GRID_G, 256, 0, stream>>>(bufC8, rowptr, col, agg);
    k_linear_mfma<false, false><<<GRID_L, 256, 0, stream>>>(agg, bufC, Wt3, bl3, bufA, bufA8);

    // ---- pool + final ----
    hipMemsetAsync(pooled, 0, NGRAPH * DIM * sizeof(float) + NGRAPH * sizeof(float), stream);
    k_pool<<<(N_NODES + 63) / 64, 256, 0, stream>>>(bufA, batch, pooled, gcnt);
    k_final<<<1, 128, 0, stream>>>(pooled, gcnt, Wlin, blin, out);
}

// Round 11
// 355.923 us; speedup vs baseline: 1.6966x; 1.1182x over previous
//
#include <hip/hip_runtime.h>

#define N_NODES 100000
#define N_EDGES 1600000
#define DIM 128
#define NGRAPH 64
#define M_PAD 100096   // 782 * 128 = 1564 * 64
#define NBUCKET 782    // ceil(100000 / 128)
#define BCAP 4096      // staging capacity per bucket (mean 2046, sigma ~45)
#define CHUNK 8192     // edges per scatter block
#define SCAT_B 196     // scatter blocks in k_prep
#define XCV_B 3125     // x-convert blocks in k_prep (12.8M floats / 4096)
#define WCV_B 24       // W-convert blocks in k_prep (98304 / 4096)

typedef __attribute__((ext_vector_type(8))) short bf16x8;
typedef __attribute__((ext_vector_type(4))) float floatx4;
typedef __attribute__((ext_vector_type(2))) float floatx2;

static __device__ __forceinline__ unsigned int f2bf(float f) {
    unsigned int u = __builtin_bit_cast(unsigned int, f);
    return (u + 0x7FFFu + ((u >> 16) & 1u)) >> 16;
}
static __device__ __forceinline__ float bf2f(unsigned short b) {
    unsigned int u = ((unsigned int)b) << 16;
    return __builtin_bit_cast(float, u);
}
static __device__ __forceinline__ unsigned int pk_fp8x4(float a, float b, float c, float d) {
    unsigned int r = 0;
    r = __builtin_amdgcn_cvt_pk_fp8_f32(a, b, r, false);
    r = __builtin_amdgcn_cvt_pk_fp8_f32(c, d, r, true);
    return r;
}
// async global->LDS DMA, 16B per lane; lds dest = (wave-uniform) base + lane*16
static __device__ __forceinline__ void gld_lds16(const void* g, void* l) {
    __builtin_amdgcn_global_load_lds(
        (const __attribute__((address_space(1))) unsigned int*)g,
        (__attribute__((address_space(3))) unsigned int*)l, 16, 0, 0);
}

// ---------------- fused prep: edge scatter + x->bf16+fp8 + W transpose + pool zero ----------------
// blocks [0,SCAT_B): bucketed edge scatter (LDS histogram + chunk reservation)
// blocks [SCAT_B, +XCV_B): x conversion. blocks [.., +WCV_B): W transpose.
// last block: zero pooled/gcnt (folds the hipMemsetAsync dispatch away).

__global__ __launch_bounds__(1024) void k_prep(
    const int* __restrict__ src, const int* __restrict__ dst,
    int* __restrict__ bcur, unsigned int* __restrict__ staging,
    const float* __restrict__ x, unsigned short* __restrict__ xb,
    unsigned char* __restrict__ x8,
    const float* __restrict__ Wl1, const float* __restrict__ Wr1,
    unsigned short* __restrict__ Wt1,
    const float* __restrict__ Wl2, const float* __restrict__ Wr2,
    unsigned short* __restrict__ Wt2,
    const float* __restrict__ Wl3, const float* __restrict__ Wr3,
    unsigned short* __restrict__ Wt3,
    float* __restrict__ pooled, float* __restrict__ gcnt) {
    int b = blockIdx.x;
    int tid = threadIdx.x;
    if (b < SCAT_B) {
        __shared__ int cnt[NBUCKET];
        __shared__ int gbase[NBUCKET];
        __shared__ int pos[NBUCKET];
        int e0 = b * CHUNK;
        for (int i = tid; i < NBUCKET; i += 1024) {
            cnt[i] = 0;
            pos[i] = 0;
        }
        __syncthreads();
        int s[8], d[8];
#pragma unroll
        for (int j = 0; j < 8; j++) {
            int e = e0 + j * 1024 + tid;
            if (e < N_EDGES) {
                s[j] = src[e];
                d[j] = dst[e];
                atomicAdd(&cnt[d[j] >> 7], 1);
            } else {
                d[j] = -1;
            }
        }
        __syncthreads();
        for (int i = tid; i < NBUCKET; i += 1024) {
            int c = cnt[i];
            if (c > 0) gbase[i] = atomicAdd(&bcur[i], c);
        }
        __syncthreads();
#pragma unroll
        for (int j = 0; j < 8; j++) {
            if (d[j] >= 0) {
                int bk = d[j] >> 7;
                int gp = gbase[bk] + atomicAdd(&pos[bk], 1);
                if (gp < BCAP)
                    staging[(size_t)bk * BCAP + gp] =
                        (unsigned int)s[j] | ((unsigned int)(d[j] & 127) << 25);
            }
        }
    } else if (b < SCAT_B + XCV_B) {
        size_t i = ((size_t)(b - SCAT_B) * 1024 + tid) * 4;
        float4 v = *(const float4*)(x + i);
        uint2 o;
        o.x = f2bf(v.x) | (f2bf(v.y) << 16);
        o.y = f2bf(v.z) | (f2bf(v.w) << 16);
        *(uint2*)(xb + i) = o;
        *(unsigned int*)(x8 + i) = pk_fp8x4(v.x, v.y, v.z, v.w);
    } else if (b < SCAT_B + XCV_B + WCV_B) {
        int base = (b - SCAT_B - XCV_B) * 4096 + tid * 4;
#pragma unroll
        for (int j = 0; j < 4; j++) {
            int id = base + j;                 // 0..98303
            int layer = id >> 15;
            int rem = id & 32767;
            int n = rem >> 8, k = rem & 255;
            const float* Wl = layer == 0 ? Wl1 : (layer == 1 ? Wl2 : Wl3);
            const float* Wr = layer == 0 ? Wr1 : (layer == 1 ? Wr2 : Wr3);
            unsigned short* Wt = layer == 0 ? Wt1 : (layer == 1 ? Wt2 : Wt3);
            float v = (k < 128) ? Wl[k * 128 + n] : Wr[(k - 128) * 128 + n];
            Wt[n * 256 + k] = (unsigned short)f2bf(v);
        }
    } else {
        for (int i = tid; i < NGRAPH * DIM; i += 1024) pooled[i] = 0.f;
        if (tid < NGRAPH) gcnt[tid] = 0.f;
    }
}

// ---------------- per-bucket counting sort with self-computed prefix ----------------
// (k_bscan folded in: each block sums bcur[0..b) itself — 782 L2-hot loads.)

__global__ __launch_bounds__(256) void k_bsort(const unsigned int* __restrict__ staging,
                                               const int* __restrict__ bcur,
                                               int* __restrict__ rowptr,
                                               int* __restrict__ col) {
    __shared__ unsigned int lpk[BCAP];
    __shared__ int lcol[BCAP];
    __shared__ int loff[129];
    __shared__ int lcur[128];
    __shared__ int red[256];
    int b = blockIdx.x, tid = threadIdx.x;
    // exclusive prefix over buckets: gbase = sum bcur[0..b)
    int partial = 0;
    for (int i = tid; i < b; i += 256) partial += bcur[i];
    red[tid] = partial;
    if (tid < 128) {
        loff[tid] = 0;
        lcur[tid] = 0;
    }
    __syncthreads();
    for (int o = 128; o > 0; o >>= 1) {
        if (tid < o) red[tid] += red[tid + o];
        __syncthreads();
    }
    int gbase = red[0];
    int nE = bcur[b];
    if (nE > BCAP) nE = BCAP;
    const unsigned int* sb = staging + (size_t)b * BCAP;
    for (int i = tid; i < nE; i += 256) {
        unsigned int p = sb[i];
        lpk[i] = p;
        atomicAdd(&loff[p >> 25], 1);
    }
    __syncthreads();
    if (tid < 64) {
        int c0 = loff[2 * tid], c1 = loff[2 * tid + 1];
        int ps = c0 + c1;
        for (int o = 1; o < 64; o <<= 1) {
            int t = __shfl_up(ps, o);
            if (tid >= o) ps += t;
        }
        int excl = ps - (c0 + c1);
        loff[2 * tid] = excl;
        loff[2 * tid + 1] = excl + c0;
        if (tid == 63) loff[128] = ps;
    }
    __syncthreads();
    if (tid < 128) {
        int idx = b * 128 + tid;
        if (idx < N_NODES) rowptr[idx] = gbase + loff[tid];
    }
    if (tid == 0 && b == NBUCKET - 1) rowptr[N_NODES] = N_EDGES;
    for (int i = tid; i < nE; i += 256) {
        unsigned int p = lpk[i];
        int d = p >> 25;
        int pos = loff[d] + atomicAdd(&lcur[d], 1);
        lcol[pos] = (int)(p & 0x1FFFFFFu);
    }
    __syncthreads();
    for (int i = tid; i < nE; i += 256) col[gbase + i] = lcol[i];
}

// ---------------- mean aggregation: fp8 in, bf16 out, 16B lanes ----------------
// 2 nodes per wave: lane = half*32 + slot*8 + chunk. Slot g in [0,4) handles
// edges start+g, start+g+4, ... (same partition as r10); chunk t8 covers dims
// t8*16..+15 (16B uint4 loads -> one wave-load = 8 rows = 16 lines; unroll 2
// keeps 32 lines in flight/wave, 2x r10). Reduce over slot bits: shfl_xor 8,16.

__global__ __launch_bounds__(256) void k_gather_f8(
    const unsigned char* __restrict__ hin8, const int* __restrict__ rowptr,
    const int* __restrict__ col, unsigned short* __restrict__ agg) {
    int lane = threadIdx.x & 63;
    int half = lane >> 5;
    int g = (lane >> 3) & 3;
    int t8 = lane & 7;
    int node = blockIdx.x * 8 + (threadIdx.x >> 6) * 2 + half;
    int start = rowptr[node], end = rowptr[node + 1];
    floatx2 a2[8];
#pragma unroll
    for (int j = 0; j < 8; j++) a2[j] = (floatx2){0.f, 0.f};
    const size_t toff = (size_t)t8 * 16;

    int c = start + g;
    while (c + 4 < end) {
        int ia = col[c], ib = col[c + 4];
        uint4 va = *(const uint4*)(hin8 + (size_t)ia * DIM + toff);
        uint4 vb = *(const uint4*)(hin8 + (size_t)ib * DIM + toff);
        const unsigned int* pa = &va.x;
        const unsigned int* pb = &vb.x;
#pragma unroll
        for (int j = 0; j < 4; j++) {
            a2[2 * j + 0] += __builtin_amdgcn_cvt_pk_f32_fp8(pa[j], false);
            a2[2 * j + 1] += __builtin_amdgcn_cvt_pk_f32_fp8(pa[j], true);
            a2[2 * j + 0] += __builtin_amdgcn_cvt_pk_f32_fp8(pb[j], false);
            a2[2 * j + 1] += __builtin_amdgcn_cvt_pk_f32_fp8(pb[j], true);
        }
        c += 8;
    }
    if (c < end) {
        int ia = col[c];
        uint4 va = *(const uint4*)(hin8 + (size_t)ia * DIM + toff);
        const unsigned int* pa = &va.x;
#pragma unroll
        for (int j = 0; j < 4; j++) {
            a2[2 * j + 0] += __builtin_amdgcn_cvt_pk_f32_fp8(pa[j], false);
            a2[2 * j + 1] += __builtin_amdgcn_cvt_pk_f32_fp8(pa[j], true);
        }
    }
    float acc[16];
#pragma unroll
    for (int j = 0; j < 8; j++) {
        acc[2 * j] = a2[j].x;
        acc[2 * j + 1] = a2[j].y;
    }
#pragma unroll
    for (int j = 0; j < 16; j++) {
        acc[j] += __shfl_xor(acc[j], 8);
        acc[j] += __shfl_xor(acc[j], 16);
    }
    if (g == 0) {
        int deg = end - start;
        float scale = 1.f / (float)(deg > 0 ? deg : 1);
        uint4 o0, o1;
        unsigned int* p0 = &o0.x;
        unsigned int* p1 = &o1.x;
#pragma unroll
        for (int j = 0; j < 4; j++) {
            p0[j] = f2bf(acc[2 * j] * scale) | (f2bf(acc[2 * j + 1] * scale) << 16);
            p1[j] = f2bf(acc[8 + 2 * j] * scale) | (f2bf(acc[8 + 2 * j + 1] * scale) << 16);
        }
        *(uint4*)(agg + (size_t)node * DIM + t8 * 16) = o0;
        *(uint4*)(agg + (size_t)node * DIM + t8 * 16 + 8) = o1;
    }
}

// ---------------- fused linear via MFMA, async-LDS-staged A (r10-proven) ----------------

template <bool RELU, bool STORE8>
__global__ __launch_bounds__(256) void k_linear_mfma(
    const unsigned short* __restrict__ aggb, const unsigned short* __restrict__ hb,
    const unsigned short* __restrict__ Wt, const float* __restrict__ bl,
    unsigned short* __restrict__ hout, unsigned char* __restrict__ hout8) {
    __shared__ unsigned char Alds[32768];  // [0,16K): agg tile, [16K,32K): h tile
    int tid = threadIdx.x;
    int w = tid >> 6, lane = tid & 63;
    int t = lane & 15, q = lane >> 4;
    size_t i0 = (size_t)blockIdx.x * 64;

#pragma unroll
    for (int k = 0; k < 4; k++) {
        int rowc = w * 16 + k * 4 + (lane >> 4);
        int s = lane & 15;
        int c = s ^ (rowc & 15);
        const unsigned short* ga = aggb + (i0 + rowc) * DIM + c * 8;
        const unsigned short* gh = hb + (i0 + rowc) * DIM + c * 8;
        gld_lds16(ga, Alds + (w * 16 + k * 4) * 256);
        gld_lds16(gh, Alds + 16384 + (w * 16 + k * 4) * 256);
    }

    bf16x8 bfrag[2][8];
#pragma unroll
    for (int ct2 = 0; ct2 < 2; ct2++)
#pragma unroll
        for (int ks = 0; ks < 8; ks++)
            bfrag[ct2][ks] =
                *(const bf16x8*)(Wt + (size_t)(w * 32 + ct2 * 16 + t) * 256 + ks * 32 + q * 8);

    floatx4 acc[4][2];
#pragma unroll
    for (int rt = 0; rt < 4; rt++)
#pragma unroll
        for (int c = 0; c < 2; c++) acc[rt][c] = (floatx4){0.f, 0.f, 0.f, 0.f};

    __syncthreads();

#pragma unroll
    for (int ks = 0; ks < 8; ks++) {
        int half = (ks < 4) ? 0 : 16384;
        int kk = ks & 3;
        int s = ((kk * 4 + q) ^ t) * 16;
        bf16x8 af[4];
#pragma unroll
        for (int rt = 0; rt < 4; rt++)
            af[rt] = *(const bf16x8*)(Alds + half + (rt * 16 + t) * 256 + s);
#pragma unroll
        for (int rt = 0; rt < 4; rt++) {
            acc[rt][0] = __builtin_amdgcn_mfma_f32_16x16x32_bf16(af[rt], bfrag[0][ks],
                                                                 acc[rt][0], 0, 0, 0);
            acc[rt][1] = __builtin_amdgcn_mfma_f32_16x16x32_bf16(af[rt], bfrag[1][ks],
                                                                 acc[rt][1], 0, 0, 0);
        }
    }

    float b0 = bl[w * 32 + t];
    float b1 = bl[w * 32 + 16 + t];
#pragma unroll
    for (int rt = 0; rt < 4; rt++) {
#pragma unroll
        for (int r = 0; r < 4; r++) {
            size_t row = i0 + rt * 16 + q * 4 + r;
            float v0 = acc[rt][0][r] + b0;
            float v1 = acc[rt][1][r] + b1;
            if (RELU) {
                v0 = fmaxf(v0, 0.f);
                v1 = fmaxf(v1, 0.f);
            }
            hout[row * DIM + w * 32 + t] = (unsigned short)f2bf(v0);
            hout[row * DIM + w * 32 + 16 + t] = (unsigned short)f2bf(v1);
            if (STORE8) {
                unsigned int pk = __builtin_amdgcn_cvt_pk_fp8_f32(v0, v1, 0u, false);
                hout8[row * DIM + w * 32 + t] = (unsigned char)(pk & 0xFF);
                hout8[row * DIM + w * 32 + 16 + t] = (unsigned char)((pk >> 8) & 0xFF);
            }
        }
    }
}

// ---------------- per-graph mean pool (batch sorted), bf16 input ----------------

__global__ void k_pool(const unsigned short* __restrict__ h, const int* __restrict__ batch,
                       float* __restrict__ pooled, float* __restrict__ gcnt) {
    int tid = threadIdx.x;
    int d = tid & 127, half = tid >> 7;
    int n0 = blockIdx.x * 64 + half * 32;
    if (n0 >= N_NODES) return;
    int nend = n0 + 32;
    if (nend > N_NODES) nend = N_NODES;
    float acc = 0.f;
    int cur = batch[n0];
    int run = 0;
    for (int n = n0; n < nend; n++) {
        int g = batch[n];
        if (g != cur) {
            atomicAdd(&pooled[cur * DIM + d], acc);
            if (d == 0) atomicAdd(&gcnt[cur], (float)run);
            acc = 0.f; run = 0; cur = g;
        }
        acc += bf2f(h[(size_t)n * DIM + d]);
        run++;
    }
    atomicAdd(&pooled[cur * DIM + d], acc);
    if (d == 0) atomicAdd(&gcnt[cur], (float)run);
}

__global__ void k_final(const float* __restrict__ pooled, const float* __restrict__ gcnt,
                        const float* __restrict__ Wlin, const float* __restrict__ blin,
                        float* __restrict__ out) {
    int t = threadIdx.x;  // 128 threads
    int g = t >> 1, o = t & 1;
    float sum = 0.f;
#pragma unroll 8
    for (int k = 0; k < DIM; k++) sum += pooled[g * DIM + k] * Wlin[k * 2 + o];
    float c = gcnt[g];
    out[g * 2 + o] = sum / fmaxf(c, 1.f) + blin[o];
}

// ---------------- launch ----------------

static inline size_t align_up(size_t v, size_t a) { return (v + a - 1) & ~(a - 1); }

extern "C" void kernel_launch(void* const* d_in, const int* in_sizes, int n_in,
                              void* d_out, int out_size, void* d_ws, size_t ws_size,
                              hipStream_t stream) {
    const float* x     = (const float*)d_in[0];
    const int*   ei    = (const int*)d_in[1];
    const int*   src   = ei;
    const int*   dst   = ei + N_EDGES;
    const int*   batch = (const int*)d_in[2];
    const float* Wl1 = (const float*)d_in[3];
    const float* bl1 = (const float*)d_in[4];
    const float* Wr1 = (const float*)d_in[5];
    const float* Wl2 = (const float*)d_in[6];
    const float* bl2 = (const float*)d_in[7];
    const float* Wr2 = (const float*)d_in[8];
    const float* Wl3 = (const float*)d_in[9];
    const float* bl3 = (const float*)d_in[10];
    const float* Wr3 = (const float*)d_in[11];
    const float* Wlin = (const float*)d_in[12];
    const float* blin = (const float*)d_in[13];
    float* out = (float*)d_out;

    char* p = (char*)d_ws;
    size_t off = 0;
    auto carve = [&](size_t bytes) -> void* {
        void* r = p + off;
        off = align_up(off + bytes, 256);
        return r;
    };
    int* rowptr = (int*)carve((N_NODES + 1) * sizeof(int));
    int* bcur   = (int*)carve(NBUCKET * sizeof(int));
    int* col    = (int*)carve((size_t)N_EDGES * sizeof(int));
    unsigned short* bufA = (unsigned short*)carve((size_t)M_PAD * DIM * 2);
    unsigned short* bufB = (unsigned short*)carve((size_t)M_PAD * DIM * 2);
    unsigned short* bufC = (unsigned short*)carve((size_t)M_PAD * DIM * 2);
    unsigned short* agg  = (unsigned short*)carve((size_t)M_PAD * DIM * 2);
    unsigned char*  bufA8 = (unsigned char*)carve((size_t)M_PAD * DIM);
    unsigned char*  bufB8 = (unsigned char*)carve((size_t)M_PAD * DIM);
    unsigned char*  bufC8 = (unsigned char*)carve((size_t)M_PAD * DIM);
    unsigned short* Wt1  = (unsigned short*)carve(256 * 128 * 2);
    unsigned short* Wt2  = (unsigned short*)carve(256 * 128 * 2);
    unsigned short* Wt3  = (unsigned short*)carve(256 * 128 * 2);
    float* pooled = (float*)carve((size_t)NGRAPH * DIM * sizeof(float));
    float* gcnt   = (float*)carve((size_t)NGRAPH * sizeof(float));
    // staging (12.8 MB) aliases bufB: dead after k_bsort; bufB first written
    // by layer 1's linear later on the same stream.
    unsigned int* staging = (unsigned int*)bufB;

    // ---- prep: edge scatter + conversions + pool zeroing in one dispatch ----
    hipMemsetAsync(bcur, 0, NBUCKET * sizeof(int), stream);
    k_prep<<<SCAT_B + XCV_B + WCV_B + 1, 1024, 0, stream>>>(
        src, dst, bcur, staging, x, bufA, bufA8,
        Wl1, Wr1, Wt1, Wl2, Wr2, Wt2, Wl3, Wr3, Wt3, pooled, gcnt);
    k_bsort<<<NBUCKET, 256, 0, stream>>>(staging, bcur, rowptr, col);

    const int GRID_G = N_NODES / 8;  // 12500
    const int GRID_L = M_PAD / 64;   // 1564

    // ---- layer 1 ----
    k_gather_f8<<<GRID_G, 256, 0, stream>>>(bufA8, rowptr, col, agg);
    k_linear_mfma<true, true><<<GRID_L, 256, 0, stream>>>(agg, bufA, Wt1, bl1, bufB, bufB8);
    // ---- layer 2 ----
    k_gather_f8<<<GRID_G, 256, 0, stream>>>(bufB8, rowptr, col, agg);
    k_linear_mfma<true, true><<<GRID_L, 256, 0, stream>>>(agg, bufB, Wt2, bl2, bufC, bufC8);
    // ---- layer 3 ----
    k_gather_f8<<<GRID_G, 256, 0, stream>>>(bufC8, rowptr, col, agg);
    k_linear_mfma<false, false><<<GRID_L, 256, 0, stream>>>(agg, bufC, Wt3, bl3, bufA, bufA8);

    // ---- pool + final ----
    k_pool<<<(N_NODES + 63) / 64, 256, 0, stream>>>(bufA, batch, pooled, gcnt);
    k_final<<<1, 128, 0, stream>>>(pooled, gcnt, Wlin, blin, out);
}